// Round 5
// baseline (340.157 us; speedup 1.0000x reference)
//
#include <hip/hip_runtime.h>
#include <math.h>

#define BN_   2048
#define INDIM 1024
#define HD    256
#define OD    512
#define TN    12
#define KN    3
#define NHOPS 4
#define TP1   13

#define ROWS  16
#define RBLK  (BN_ / ROWS)   // 128

// async global -> LDS, 16B per lane (LDS dest linear in tid)
__device__ __forceinline__ void gll16(const float* g, float* l) {
  __builtin_amdgcn_global_load_lds(
      (const __attribute__((address_space(1))) void*)g,
      (__attribute__((address_space(3))) void*)l, 16, 0, 0);
}

__device__ __forceinline__ float4 ld4(const float* p) { return *(const float4*)p; }

__device__ __forceinline__ void fma4(float4& c, float a, const float4 b) {
  c.x = fmaf(a, b.x, c.x); c.y = fmaf(a, b.y, c.y);
  c.z = fmaf(a, b.z, c.z); c.w = fmaf(a, b.w, c.w);
}
__device__ __forceinline__ void add4(float4& c, const float4 b) {
  c.x += b.x; c.y += b.y; c.z += b.z; c.w += b.w;
}

// ---- barrier-free K loop: acc[16] += A[16rows x k-slice] @ W[k-slice x 4cols]
#define KLOOP(SA, ASTR, WROW0, WS, NK4, KS0)                                   \
  do {                                                                         \
    const float* wp_ = (WROW0);                                                \
    float4 wA0 = ld4(wp_), wA1 = ld4(wp_ + (WS)), wA2 = ld4(wp_ + 2 * (WS)),   \
           wA3 = ld4(wp_ + 3 * (WS));                                          \
    _Pragma("unroll 1")                                                        \
    for (int k4_ = 0; k4_ < (NK4) - 1; ++k4_) {                                \
      const float* wn_ = wp_ + 4 * (WS);                                       \
      float4 wB0 = ld4(wn_), wB1 = ld4(wn_ + (WS)), wB2 = ld4(wn_ + 2 * (WS)), \
             wB3 = ld4(wn_ + 3 * (WS));                                        \
      const int kk_ = (KS0) + k4_ * 4;                                         \
      _Pragma("unroll")                                                        \
      for (int r_ = 0; r_ < 16; ++r_) {                                        \
        float4 av = *(const float4*)((SA) + r_ * (ASTR) + kk_);                \
        fma4(acc[r_], av.x, wA0); fma4(acc[r_], av.y, wA1);                    \
        fma4(acc[r_], av.z, wA2); fma4(acc[r_], av.w, wA3);                    \
      }                                                                        \
      wA0 = wB0; wA1 = wB1; wA2 = wB2; wA3 = wB3; wp_ = wn_;                   \
    }                                                                          \
    const int kk_ = (KS0) + ((NK4) - 1) * 4;                                   \
    _Pragma("unroll")                                                          \
    for (int r_ = 0; r_ < 16; ++r_) {                                          \
      float4 av = *(const float4*)((SA) + r_ * (ASTR) + kk_);                  \
      fma4(acc[r_], av.x, wA0); fma4(acc[r_], av.y, wA1);                      \
      fma4(acc[r_], av.z, wA2); fma4(acc[r_], av.w, wA3);                      \
    }                                                                          \
  } while (0)

#define PST(B) { _Pragma("unroll") for (int r = 0; r < 16; ++r) B[r][tx] = acc[r]; }
#define PAD(B) { _Pragma("unroll") for (int r = 0; r < 16; ++r) add4(acc[r], B[r][tx]); }

// deterministic 8-wave reduction, fixed association ((0+1)+(2+3))+((4+5)+(6+7));
// wave 0 ends with full sum.
#define REDUCE8()                                                              \
  do {                                                                         \
    __syncthreads();                                                           \
    if (w == 1) PST(pbA) else if (w == 3) PST(pbB)                             \
    __syncthreads();                                                           \
    if (w == 0) PAD(pbA) else if (w == 2) PAD(pbB)                             \
    __syncthreads();                                                           \
    if (w == 5) PST(pbA) else if (w == 7) PST(pbB)                             \
    __syncthreads();                                                           \
    if (w == 4) PAD(pbA) else if (w == 6) PAD(pbB)                             \
    __syncthreads();                                                           \
    if (w == 2) PST(pbA) else if (w == 6) PST(pbB)                             \
    __syncthreads();                                                           \
    if (w == 0) PAD(pbA) else if (w == 4) PAD(pbB)                             \
    __syncthreads();                                                           \
    if (w == 4) PST(pbA)                                                       \
    __syncthreads();                                                           \
    if (w == 0) PAD(pbA)                                                       \
  } while (0)

// ---------------- init: build hop-0 grouping via atomics ----------------
__global__ __launch_bounds__(256) void k_init(const int* __restrict__ init_t,
                                              int* __restrict__ cnt,
                                              int* __restrict__ gidx) {
  int n = blockIdx.x * 256 + threadIdx.x;
  if (n < BN_) {
    int t = init_t[n];
    int slot = atomicAdd(&cnt[t], 1);
    gidx[t * BN_ + slot] = n;
  }
}

// ---------------- gemm_in partial: pp[kh] = x[:, kh*512:+512] @ W_in[kh*512:+512, :] ----------------
__global__ __launch_bounds__(512, 4) void k_gemm_in(const float* __restrict__ A,
                                                    const float* __restrict__ W,
                                                    float* __restrict__ pp) {
  const int bm = blockIdx.x * ROWS;
  const int kh = blockIdx.y;
  __shared__ float  sA[ROWS][512];     // 32KB
  __shared__ float4 pbA[16][64];       // 16KB
  __shared__ float4 pbB[16][64];       // 16KB
  const int tid = threadIdx.x;
  const int tx = tid & 63;
  const int w = tid >> 6;

#pragma unroll
  for (int l = 0; l < 4; ++l) {
    int idx = tid + l * 512;
    int r = idx >> 7;                  // wave-uniform
    int c = (idx & 127) << 2;
    gll16(&A[(size_t)(bm + r) * INDIM + kh * 512 + c], &sA[r][c]);
  }
  __syncthreads();

  float4 acc[16];
#pragma unroll
  for (int r = 0; r < 16; ++r) acc[r] = make_float4(0.f, 0.f, 0.f, 0.f);

  const int ks = w * 64;
  KLOOP(&sA[0][0], 512, W + (size_t)(kh * 512 + ks) * HD + tx * 4, HD, 16, ks);
  REDUCE8();

  if (w == 0) {
#pragma unroll
    for (int r = 0; r < 16; ++r)
      *(float4*)&pp[((size_t)kh * BN_ + bm + r) * HD + tx * 4] = acc[r];
  }
}

// ---------------- combine gemm_in partials + bias ----------------
__global__ __launch_bounds__(256) void k_cin(const float* __restrict__ pp,
                                             const float* __restrict__ bias,
                                             float* __restrict__ states) {
  int idx = blockIdx.x * 256 + threadIdx.x;     // float4 index
  int c = (idx & 63) << 2;
  float4 a = ld4(&pp[(size_t)idx * 4]);
  float4 b = ld4(&pp[(size_t)BN_ * HD + (size_t)idx * 4]);
  float4 bv = ld4(&bias[c]);
  float4 o = make_float4(a.x + b.x + bv.x, a.y + b.y + bv.y,
                         a.z + b.z + bv.z, a.w + b.w + bv.w);
  *(float4*)&states[(size_t)idx * 4] = o;
}

// ---------------- gemm_out: out = states @ W_out + b_out ----------------
__global__ __launch_bounds__(512, 4) void k_gemm_out(const float* __restrict__ A,
                                                     const float* __restrict__ W,
                                                     const float* __restrict__ bias,
                                                     float* __restrict__ C) {
  const int bm = blockIdx.x * ROWS;
  const int cb = blockIdx.y * 256;
  __shared__ float  sA[ROWS][HD];      // 16KB
  __shared__ float4 pbA[16][64];
  __shared__ float4 pbB[16][64];
  const int tid = threadIdx.x;
  const int tx = tid & 63;
  const int w = tid >> 6;

#pragma unroll
  for (int l = 0; l < 2; ++l) {
    int idx = tid + l * 512;
    int r = idx >> 6;                  // wave-uniform (= w + 8l)
    int c = (idx & 63) << 2;
    gll16(&A[(size_t)(bm + r) * HD + c], &sA[r][c]);
  }
  __syncthreads();

  float4 acc[16];
#pragma unroll
  for (int r = 0; r < 16; ++r) acc[r] = make_float4(0.f, 0.f, 0.f, 0.f);

  const int ks = w * 32;
  KLOOP(&sA[0][0], HD, W + (size_t)ks * OD + cb + tx * 4, OD, 8, ks);
  REDUCE8();

  if (w == 0) {
    float4 bv = ld4(&bias[cb + tx * 4]);
#pragma unroll
    for (int r = 0; r < 16; ++r) {
      float4 o = make_float4(acc[r].x + bv.x, acc[r].y + bv.y,
                             acc[r].z + bv.z, acc[r].w + bv.w);
      *(float4*)&C[(size_t)(bm + r) * OD + cb + tx * 4] = o;
    }
  }
}

// ---------------- fused expert: part_k[n] = wk*relu(relu(S@W1+b1)@W2+b2) ----------------
__global__ __launch_bounds__(512, 4) void k_h1h2(
    int hop,
    const float* __restrict__ W1, const float* __restrict__ b1,
    const float* __restrict__ W2, const float* __restrict__ b2,
    const float* __restrict__ op_noise,
    const int* __restrict__ cnt, const int* __restrict__ gidx,
    const float* __restrict__ states, float* __restrict__ part) {
  // XCD-cluster: residue (bid%8) pins a temper class to one XCD's L2
  const int bid = blockIdx.x;
  const int res = bid & 7;
  const int slot = bid >> 3;
  int t, rb;
  if (slot < RBLK) { t = res; rb = slot; }
  else { if (res >= 4) return; t = res + 8; rb = slot - RBLK; }
  const int k = blockIdx.y;

  const int cntv = cnt[hop * 16 + t];
  const int r0 = rb * ROWS;
  if (r0 >= cntv) return;
  const int gb = (hop * TN + t) * BN_ + r0;
  const int rows = min(ROWS, cntv - r0);

  __shared__ float  sA[ROWS][HD];      // 16KB states rows
  __shared__ float  sH[ROWS][HD];      // 16KB h1
  __shared__ float4 pbA[16][64];       // 16KB
  __shared__ float4 pbB[16][64];       // 16KB
  const int tid = threadIdx.x;
  const int tx = tid & 63;
  const int w = tid >> 6;

  // gather active rows (wave-uniform r; tail rows stale -> discarded)
#pragma unroll
  for (int l = 0; l < 2; ++l) {
    int r = w + 8 * l;
    int c = tx << 2;
    if (r < rows)
      gll16(&states[(size_t)gidx[gb + r] * HD + c], &sA[r][c]);
  }
  __syncthreads();

  const float* Wa = W1 + (size_t)(t * KN + k) * HD * HD;
  const float* Wb = W2 + (size_t)(t * KN + k) * HD * HD;
  const int ks = w * 32;

  float4 acc[16];
#pragma unroll
  for (int r = 0; r < 16; ++r) acc[r] = make_float4(0.f, 0.f, 0.f, 0.f);

  // ---- layer 1 ----
  KLOOP(&sA[0][0], HD, Wa + (size_t)ks * HD + tx * 4, HD, 8, ks);
  REDUCE8();

  if (w == 0) {
    float4 bv = ld4(&b1[(t * KN + k) * HD + tx * 4]);
#pragma unroll
    for (int r = 0; r < 16; ++r) {
      float4 h;
      h.x = fmaxf(acc[r].x + bv.x, 0.f);
      h.y = fmaxf(acc[r].y + bv.y, 0.f);
      h.z = fmaxf(acc[r].z + bv.z, 0.f);
      h.w = fmaxf(acc[r].w + bv.w, 0.f);
      *(float4*)&sH[r][tx * 4] = h;
    }
  }
  __syncthreads();

  // ---- layer 2 ----
#pragma unroll
  for (int r = 0; r < 16; ++r) acc[r] = make_float4(0.f, 0.f, 0.f, 0.f);
  KLOOP(&sH[0][0], HD, Wb + (size_t)ks * HD + tx * 4, HD, 8, ks);
  REDUCE8();

  if (w == 0) {
    float wkk;
    {
      const float* on = op_noise + (hop * TN + t) * KN;
      float x0 = on[0], x1 = on[1], x2 = on[2];
      float m = fmaxf(fmaxf(x0, x1), x2);
      float e0 = expf(x0 - m), e1 = expf(x1 - m), e2 = expf(x2 - m);
      float ek = (k == 0) ? e0 : (k == 1) ? e1 : e2;
      wkk = ek / (e0 + e1 + e2);
    }
    float4 bv = ld4(&b2[(t * KN + k) * HD + tx * 4]);
#pragma unroll
    for (int r = 0; r < 16; ++r) {
      if (r < rows) {
        int n = gidx[gb + r];
        float4 o;
        o.x = wkk * fmaxf(acc[r].x + bv.x, 0.f);
        o.y = wkk * fmaxf(acc[r].y + bv.y, 0.f);
        o.z = wkk * fmaxf(acc[r].z + bv.z, 0.f);
        o.w = wkk * fmaxf(acc[r].w + bv.w, 0.f);
        *(float4*)&part[((size_t)k * BN_ + n) * HD + tx * 4] = o;
      }
    }
  }
}

// ---------------- combine partials + routing + Gumbel argmax + regroup ----------------
__global__ __launch_bounds__(256) void k_comb(
    int hop,
    const float* __restrict__ Wr, const float* __restrict__ br,
    const float* __restrict__ route_u,
    int* __restrict__ cnt, int* __restrict__ gidx,
    const float* __restrict__ part,
    float* __restrict__ states) {
  const int t  = blockIdx.x % TN;
  const int rb = blockIdx.x / TN;
  const int cntv = cnt[hop * 16 + t];
  const int r0 = rb * ROWS;
  if (r0 >= cntv) return;
  const int gb = (hop * TN + t) * BN_ + r0;
  const int rows = min(ROWS, cntv - r0);

  __shared__ float sO[ROWS][HD + 4];
  __shared__ float sWr[HD * TP1];
  __shared__ float sL[ROWS][16];
  __shared__ int   sN[ROWS];

  const int tid = threadIdx.x;
  if (tid < ROWS && tid < rows) sN[tid] = gidx[gb + tid];

#pragma unroll
  for (int l = 0; l < 4; ++l) {
    int idx = tid + l * 256;
    int r = idx >> 6;
    int c = (idx & 63) << 2;
    if (r < rows) {
      int n = gidx[gb + r];
      size_t p = (size_t)n * HD + c;
      float4 a = ld4(&part[p]);
      float4 b = ld4(&part[(size_t)BN_ * HD + p]);
      float4 cc = ld4(&part[(size_t)2 * BN_ * HD + p]);
      float4 v = make_float4(a.x + b.x + cc.x, a.y + b.y + cc.y,
                             a.z + b.z + cc.z, a.w + b.w + cc.w);
      *(float4*)&sO[r][c] = v;
      *(float4*)&states[(size_t)n * HD + c] = v;
    }
  }
  for (int i = tid; i < HD * TP1; i += 256)
    sWr[i] = Wr[(size_t)t * HD * TP1 + i];
  __syncthreads();

  int r = tid >> 4, g = tid & 15;
  if (r < rows && g < TP1) {
    float a = br[t * TP1 + g];
#pragma unroll 8
    for (int f = 0; f < HD; ++f) a = fmaf(sO[r][f], sWr[f * TP1 + g], a);
    float u = route_u[((size_t)hop * BN_ + sN[r]) * TP1 + g];
    float gb_ = -logf(-logf(u + 1e-9f) + 1e-9f);
    sL[r][g] = a + gb_;
  }
  __syncthreads();

  if (tid < rows) {
    float best = sL[tid][0];
    int bj = 0;
#pragma unroll
    for (int gg = 1; gg < TP1; ++gg) {
      float v = sL[tid][gg];
      if (v > best) { best = v; bj = gg; }
    }
    // regroup into next hop (skip done rows; bj<TN => new temper = bj)
    if (hop + 1 < NHOPS && bj != TN) {
      int n = sN[tid];
      int slot = atomicAdd(&cnt[(hop + 1) * 16 + bj], 1);
      gidx[((hop + 1) * TN + bj) * BN_ + slot] = n;
    }
  }
}

// ---------------- launcher ----------------
extern "C" void kernel_launch(void* const* d_in, const int* in_sizes, int n_in,
                              void* d_out, int out_size, void* d_ws, size_t ws_size,
                              hipStream_t stream) {
  const float* x        = (const float*)d_in[0];
  const int*   init_t   = (const int*)d_in[1];
  const float* op_noise = (const float*)d_in[2];
  const float* route_u  = (const float*)d_in[3];
  const float* W_in     = (const float*)d_in[4];
  const float* b_in     = (const float*)d_in[5];
  const float* W1       = (const float*)d_in[6];
  const float* b1       = (const float*)d_in[7];
  const float* W2       = (const float*)d_in[8];
  const float* b2       = (const float*)d_in[9];
  const float* Wr       = (const float*)d_in[10];
  const float* br       = (const float*)d_in[11];
  const float* W_out    = (const float*)d_in[12];
  const float* b_out    = (const float*)d_in[13];
  float* out = (float*)d_out;

  float* states = (float*)d_ws;                       // 2MB
  float* part   = states + (size_t)BN_ * HD;          // [KN][BN_][HD] 6MB
  float* pp     = part;                               // gemm_in partials alias
  int* cnt  = (int*)(part + (size_t)KN * BN_ * HD);   // [NHOPS][16]
  int* gidx = cnt + NHOPS * 16;                       // [NHOPS][TN][BN_]

  hipMemsetAsync(cnt, 0, NHOPS * 16 * sizeof(int), stream);
  k_init<<<(BN_ + 255) / 256, 256, 0, stream>>>(init_t, cnt, gidx);

  k_gemm_in<<<dim3(RBLK, 2), 512, 0, stream>>>(x, W_in, pp);
  k_cin<<<(BN_ * HD / 4) / 256, 256, 0, stream>>>(pp, b_in, states);

  for (int hop = 0; hop < NHOPS; ++hop) {
    k_h1h2<<<dim3(8 * 2 * RBLK, KN), 512, 0, stream>>>(
        hop, W1, b1, W2, b2, op_noise, cnt, gidx, states, part);
    k_comb<<<TN * RBLK, 256, 0, stream>>>(
        hop, Wr, br, route_u, cnt, gidx, part, states);
  }

  k_gemm_out<<<dim3(RBLK, OD / 256), 512, 0, stream>>>(states, W_out, b_out, out);
}

// Round 6
// 228.062 us; speedup vs baseline: 1.4915x; 1.4915x over previous
//
#include <hip/hip_runtime.h>
#include <math.h>

#define BN_   2048
#define INDIM 1024
#define HD    256
#define OD    512
#define TN    12
#define KN    3
#define NHOPS 4
#define TP1   13

#define ER    8              // expert/gemm row tile
#define CR    16             // comb row tile

// async global -> LDS, 16B per lane (LDS dest linear in tid)
__device__ __forceinline__ void gll16(const float* g, float* l) {
  __builtin_amdgcn_global_load_lds(
      (const __attribute__((address_space(1))) void*)g,
      (__attribute__((address_space(3))) void*)l, 16, 0, 0);
}

__device__ __forceinline__ float4 ld4(const float* p) { return *(const float4*)p; }

__device__ __forceinline__ void fma4(float4& c, float a, const float4 b) {
  c.x = fmaf(a, b.x, c.x); c.y = fmaf(a, b.y, c.y);
  c.z = fmaf(a, b.z, c.z); c.w = fmaf(a, b.w, c.w);
}
__device__ __forceinline__ void add4(float4& c, const float4 b) {
  c.x += b.x; c.y += b.y; c.z += b.z; c.w += b.w;
}

// barrier-free K loop: acc[NR] += A[NR rows x k-slice] @ W[k-slice x 4 cols]
// W streamed global->reg with 1-iteration prefetch; A broadcast from LDS.
template<int NR>
__device__ __forceinline__ void kloop(float4* acc, const float* SA, int astr,
                                      const float* w0, int ws, int nk4, int ks0) {
  const float* wp = w0;
  float4 wA0 = ld4(wp), wA1 = ld4(wp + ws), wA2 = ld4(wp + 2 * ws),
         wA3 = ld4(wp + 3 * ws);
#pragma unroll 1
  for (int k4 = 0; k4 < nk4 - 1; ++k4) {
    const float* wn = wp + 4 * ws;
    float4 wB0 = ld4(wn), wB1 = ld4(wn + ws), wB2 = ld4(wn + 2 * ws),
           wB3 = ld4(wn + 3 * ws);
    const int kk = ks0 + k4 * 4;
#pragma unroll
    for (int r = 0; r < NR; ++r) {
      float4 av = *(const float4*)(SA + r * astr + kk);
      fma4(acc[r], av.x, wA0); fma4(acc[r], av.y, wA1);
      fma4(acc[r], av.z, wA2); fma4(acc[r], av.w, wA3);
    }
    wA0 = wB0; wA1 = wB1; wA2 = wB2; wA3 = wB3; wp = wn;
  }
  const int kk = ks0 + (nk4 - 1) * 4;
#pragma unroll
  for (int r = 0; r < NR; ++r) {
    float4 av = *(const float4*)(SA + r * astr + kk);
    fma4(acc[r], av.x, wA0); fma4(acc[r], av.y, wA1);
    fma4(acc[r], av.z, wA2); fma4(acc[r], av.w, wA3);
  }
}

// deterministic 4-wave reduction, fixed association (0+1)+(2+3); wave 0 ends with sum
template<int NR>
__device__ __forceinline__ void reduce4(float4* acc, float4 (*pbA)[64],
                                        float4 (*pbB)[64], int w, int tx) {
  __syncthreads();
  if (w == 1) {
#pragma unroll
    for (int r = 0; r < NR; ++r) pbA[r][tx] = acc[r];
  } else if (w == 3) {
#pragma unroll
    for (int r = 0; r < NR; ++r) pbB[r][tx] = acc[r];
  }
  __syncthreads();
  if (w == 0) {
#pragma unroll
    for (int r = 0; r < NR; ++r) add4(acc[r], pbA[r][tx]);
  } else if (w == 2) {
#pragma unroll
    for (int r = 0; r < NR; ++r) add4(acc[r], pbB[r][tx]);
  }
  __syncthreads();
  if (w == 2) {
#pragma unroll
    for (int r = 0; r < NR; ++r) pbA[r][tx] = acc[r];
  }
  __syncthreads();
  if (w == 0) {
#pragma unroll
    for (int r = 0; r < NR; ++r) add4(acc[r], pbA[r][tx]);
  }
}

// ---------------- init: build hop-0 grouping via atomics ----------------
__global__ __launch_bounds__(256) void k_init(const int* __restrict__ init_t,
                                              int* __restrict__ cnt,
                                              int* __restrict__ gidx) {
  int n = blockIdx.x * 256 + threadIdx.x;
  if (n < BN_) {
    int t = init_t[n];
    int slot = atomicAdd(&cnt[t], 1);
    gidx[t * BN_ + slot] = n;
  }
}

// ---------------- gemm_in partial: pp[kh] = x[:, kh*512:+512] @ W_in[kh*512:+512, :] ----------------
__global__ __launch_bounds__(256) void k_gemm_in(const float* __restrict__ A,
                                                 const float* __restrict__ W,
                                                 float* __restrict__ pp) {
  const int bm = blockIdx.x * ER;
  const int kh = blockIdx.y;
  __shared__ float  sA[ER][512];       // 16KB
  __shared__ float4 pbA[ER][64];       // 8KB
  __shared__ float4 pbB[ER][64];       // 8KB
  const int tid = threadIdx.x;
  const int tx = tid & 63;
  const int w = tid >> 6;

#pragma unroll
  for (int l = 0; l < 4; ++l) {
    int idx = tid + l * 256;
    int r = idx >> 7;                  // wave-uniform
    int c = (idx & 127) << 2;
    gll16(&A[(size_t)(bm + r) * INDIM + kh * 512 + c], &sA[r][c]);
  }
  __syncthreads();

  float4 acc[ER];
#pragma unroll
  for (int r = 0; r < ER; ++r) acc[r] = make_float4(0.f, 0.f, 0.f, 0.f);

  const int ks = w * 128;
  kloop<ER>(acc, &sA[0][0], 512, W + (size_t)(kh * 512 + ks) * HD + tx * 4, HD, 32, ks);
  reduce4<ER>(acc, pbA, pbB, w, tx);

  if (w == 0) {
#pragma unroll
    for (int r = 0; r < ER; ++r)
      *(float4*)&pp[((size_t)kh * BN_ + bm + r) * HD + tx * 4] = acc[r];
  }
}

// ---------------- combine gemm_in partials + bias ----------------
__global__ __launch_bounds__(256) void k_cin(const float* __restrict__ pp,
                                             const float* __restrict__ bias,
                                             float* __restrict__ states) {
  int idx = blockIdx.x * 256 + threadIdx.x;     // float4 index
  int c = (idx & 63) << 2;
  float4 a = ld4(&pp[(size_t)idx * 4]);
  float4 b = ld4(&pp[(size_t)BN_ * HD + (size_t)idx * 4]);
  float4 bv = ld4(&bias[c]);
  float4 o = make_float4(a.x + b.x + bv.x, a.y + b.y + bv.y,
                         a.z + b.z + bv.z, a.w + b.w + bv.w);
  *(float4*)&states[(size_t)idx * 4] = o;
}

// ---------------- gemm_out: out = states @ W_out + b_out ----------------
__global__ __launch_bounds__(256) void k_gemm_out(const float* __restrict__ A,
                                                  const float* __restrict__ W,
                                                  const float* __restrict__ bias,
                                                  float* __restrict__ C) {
  const int bm = blockIdx.x * ER;
  const int cb = blockIdx.y * 256;
  __shared__ float  sA[ER][HD];        // 8KB
  __shared__ float4 pbA[ER][64];
  __shared__ float4 pbB[ER][64];
  const int tid = threadIdx.x;
  const int tx = tid & 63;
  const int w = tid >> 6;

#pragma unroll
  for (int l = 0; l < 2; ++l) {
    int idx = tid + l * 256;
    int r = idx >> 6;                  // wave-uniform (w + 4l)
    int c = (idx & 63) << 2;
    gll16(&A[(size_t)(bm + r) * HD + c], &sA[r][c]);
  }
  __syncthreads();

  float4 acc[ER];
#pragma unroll
  for (int r = 0; r < ER; ++r) acc[r] = make_float4(0.f, 0.f, 0.f, 0.f);

  const int ks = w * 64;
  kloop<ER>(acc, &sA[0][0], HD, W + (size_t)ks * OD + cb + tx * 4, OD, 16, ks);
  reduce4<ER>(acc, pbA, pbB, w, tx);

  if (w == 0) {
    float4 bv = ld4(&bias[cb + tx * 4]);
#pragma unroll
    for (int r = 0; r < ER; ++r) {
      float4 o = make_float4(acc[r].x + bv.x, acc[r].y + bv.y,
                             acc[r].z + bv.z, acc[r].w + bv.w);
      *(float4*)&C[(size_t)(bm + r) * OD + cb + tx * 4] = o;
    }
  }
}

// ---------------- fused expert: part_k[n] = wk*relu(relu(S@W1+b1)@W2+b2) ----------------
// grid = (TN * 256, KN); 256 thr, 4 waves k-split (64 k each)
__global__ __launch_bounds__(256) void k_h1h2(
    int hop,
    const float* __restrict__ W1, const float* __restrict__ b1,
    const float* __restrict__ W2, const float* __restrict__ b2,
    const float* __restrict__ op_noise,
    const int* __restrict__ cnt, const int* __restrict__ gidx,
    const float* __restrict__ states, float* __restrict__ part) {
  const int t  = blockIdx.x % TN;
  const int rb = blockIdx.x / TN;
  const int k  = blockIdx.y;

  const int cntv = cnt[hop * 16 + t];
  const int r0 = rb * ER;
  if (r0 >= cntv) return;
  const int gb = (hop * TN + t) * BN_ + r0;
  const int rows = min(ER, cntv - r0);

  __shared__ float  sA[ER][HD];        // 8KB states rows
  __shared__ float  sH[ER][HD];        // 8KB h1
  __shared__ float4 pbA[ER][64];       // 8KB
  __shared__ float4 pbB[ER][64];       // 8KB  -> 32KB total
  const int tid = threadIdx.x;
  const int tx = tid & 63;
  const int w = tid >> 6;

  // gather active rows (wave-uniform r; tail rows stale -> discarded)
#pragma unroll
  for (int l = 0; l < 2; ++l) {
    int r = w + 4 * l;
    int c = tx << 2;
    if (r < rows)
      gll16(&states[(size_t)gidx[gb + r] * HD + c], &sA[r][c]);
  }
  __syncthreads();

  const float* Wa = W1 + (size_t)(t * KN + k) * HD * HD;
  const float* Wb = W2 + (size_t)(t * KN + k) * HD * HD;
  const int ks = w * 64;

  float4 acc[ER];
#pragma unroll
  for (int r = 0; r < ER; ++r) acc[r] = make_float4(0.f, 0.f, 0.f, 0.f);

  // ---- layer 1 ----
  kloop<ER>(acc, &sA[0][0], HD, Wa + (size_t)ks * HD + tx * 4, HD, 16, ks);
  reduce4<ER>(acc, pbA, pbB, w, tx);

  if (w == 0) {
    float4 bv = ld4(&b1[(t * KN + k) * HD + tx * 4]);
#pragma unroll
    for (int r = 0; r < ER; ++r) {
      float4 h;
      h.x = fmaxf(acc[r].x + bv.x, 0.f);
      h.y = fmaxf(acc[r].y + bv.y, 0.f);
      h.z = fmaxf(acc[r].z + bv.z, 0.f);
      h.w = fmaxf(acc[r].w + bv.w, 0.f);
      *(float4*)&sH[r][tx * 4] = h;
    }
  }
  __syncthreads();

  // ---- layer 2 ----
#pragma unroll
  for (int r = 0; r < ER; ++r) acc[r] = make_float4(0.f, 0.f, 0.f, 0.f);
  kloop<ER>(acc, &sH[0][0], HD, Wb + (size_t)ks * HD + tx * 4, HD, 16, ks);
  reduce4<ER>(acc, pbA, pbB, w, tx);

  if (w == 0) {
    float wkk;
    {
      const float* on = op_noise + (hop * TN + t) * KN;
      float x0 = on[0], x1 = on[1], x2 = on[2];
      float m = fmaxf(fmaxf(x0, x1), x2);
      float e0 = expf(x0 - m), e1 = expf(x1 - m), e2 = expf(x2 - m);
      float ek = (k == 0) ? e0 : (k == 1) ? e1 : e2;
      wkk = ek / (e0 + e1 + e2);
    }
    float4 bv = ld4(&b2[(t * KN + k) * HD + tx * 4]);
#pragma unroll
    for (int r = 0; r < ER; ++r) {
      if (r < rows) {
        int n = gidx[gb + r];
        float4 o;
        o.x = wkk * fmaxf(acc[r].x + bv.x, 0.f);
        o.y = wkk * fmaxf(acc[r].y + bv.y, 0.f);
        o.z = wkk * fmaxf(acc[r].z + bv.z, 0.f);
        o.w = wkk * fmaxf(acc[r].w + bv.w, 0.f);
        *(float4*)&part[((size_t)k * BN_ + n) * HD + tx * 4] = o;
      }
    }
  }
}

// ---------------- combine partials + routing + Gumbel argmax + regroup ----------------
__global__ __launch_bounds__(256) void k_comb(
    int hop,
    const float* __restrict__ Wr, const float* __restrict__ br,
    const float* __restrict__ route_u,
    int* __restrict__ cnt, int* __restrict__ gidx,
    const float* __restrict__ part,
    float* __restrict__ states) {
  const int t  = blockIdx.x % TN;
  const int rb = blockIdx.x / TN;
  const int cntv = cnt[hop * 16 + t];
  const int r0 = rb * CR;
  if (r0 >= cntv) return;
  const int gb = (hop * TN + t) * BN_ + r0;
  const int rows = min(CR, cntv - r0);

  __shared__ float sO[CR][HD + 4];
  __shared__ float sWr[HD * TP1];
  __shared__ float sL[CR][16];
  __shared__ int   sN[CR];

  const int tid = threadIdx.x;
  if (tid < CR && tid < rows) sN[tid] = gidx[gb + tid];

#pragma unroll
  for (int l = 0; l < 4; ++l) {
    int idx = tid + l * 256;
    int r = idx >> 6;
    int c = (idx & 63) << 2;
    if (r < rows) {
      int n = gidx[gb + r];
      size_t p = (size_t)n * HD + c;
      float4 a = ld4(&part[p]);
      float4 b = ld4(&part[(size_t)BN_ * HD + p]);
      float4 cc = ld4(&part[(size_t)2 * BN_ * HD + p]);
      float4 v = make_float4(a.x + b.x + cc.x, a.y + b.y + cc.y,
                             a.z + b.z + cc.z, a.w + b.w + cc.w);
      *(float4*)&sO[r][c] = v;
      *(float4*)&states[(size_t)n * HD + c] = v;
    }
  }
  for (int i = tid; i < HD * TP1; i += 256)
    sWr[i] = Wr[(size_t)t * HD * TP1 + i];
  __syncthreads();

  int r = tid >> 4, g = tid & 15;
  if (r < rows && g < TP1) {
    float a = br[t * TP1 + g];
#pragma unroll 8
    for (int f = 0; f < HD; ++f) a = fmaf(sO[r][f], sWr[f * TP1 + g], a);
    float u = route_u[((size_t)hop * BN_ + sN[r]) * TP1 + g];
    float gb_ = -logf(-logf(u + 1e-9f) + 1e-9f);
    sL[r][g] = a + gb_;
  }
  __syncthreads();

  if (tid < rows) {
    float best = sL[tid][0];
    int bj = 0;
#pragma unroll
    for (int gg = 1; gg < TP1; ++gg) {
      float v = sL[tid][gg];
      if (v > best) { best = v; bj = gg; }
    }
    // regroup into next hop (skip done rows; bj<TN => new temper = bj)
    if (hop + 1 < NHOPS && bj != TN) {
      int n = sN[tid];
      int slot = atomicAdd(&cnt[(hop + 1) * 16 + bj], 1);
      gidx[((hop + 1) * TN + bj) * BN_ + slot] = n;
    }
  }
}

// ---------------- launcher ----------------
extern "C" void kernel_launch(void* const* d_in, const int* in_sizes, int n_in,
                              void* d_out, int out_size, void* d_ws, size_t ws_size,
                              hipStream_t stream) {
  const float* x        = (const float*)d_in[0];
  const int*   init_t   = (const int*)d_in[1];
  const float* op_noise = (const float*)d_in[2];
  const float* route_u  = (const float*)d_in[3];
  const float* W_in     = (const float*)d_in[4];
  const float* b_in     = (const float*)d_in[5];
  const float* W1       = (const float*)d_in[6];
  const float* b1       = (const float*)d_in[7];
  const float* W2       = (const float*)d_in[8];
  const float* b2       = (const float*)d_in[9];
  const float* Wr       = (const float*)d_in[10];
  const float* br       = (const float*)d_in[11];
  const float* W_out    = (const float*)d_in[12];
  const float* b_out    = (const float*)d_in[13];
  float* out = (float*)d_out;

  float* states = (float*)d_ws;                       // 2MB
  float* part   = states + (size_t)BN_ * HD;          // [KN][BN_][HD] 6MB
  float* pp     = part;                               // gemm_in partials alias (4MB)
  int* cnt  = (int*)(part + (size_t)KN * BN_ * HD);   // [NHOPS][16]
  int* gidx = cnt + NHOPS * 16;                       // [NHOPS][TN][BN_]

  hipMemsetAsync(cnt, 0, NHOPS * 16 * sizeof(int), stream);
  k_init<<<(BN_ + 255) / 256, 256, 0, stream>>>(init_t, cnt, gidx);

  k_gemm_in<<<dim3(BN_ / ER, 2), 256, 0, stream>>>(x, W_in, pp);
  k_cin<<<(BN_ * HD / 4) / 256, 256, 0, stream>>>(pp, b_in, states);

  for (int hop = 0; hop < NHOPS; ++hop) {
    k_h1h2<<<dim3(TN * (BN_ / ER), KN), 256, 0, stream>>>(
        hop, W1, b1, W2, b2, op_noise, cnt, gidx, states, part);
    k_comb<<<TN * (BN_ / CR), 256, 0, stream>>>(
        hop, Wr, br, route_u, cnt, gidx, part, states);
  }

  k_gemm_out<<<dim3(BN_ / ER, OD / 256), 256, 0, stream>>>(states, W_out, b_out, out);
}

// Round 7
// 220.328 us; speedup vs baseline: 1.5439x; 1.0351x over previous
//
#include <hip/hip_runtime.h>
#include <math.h>

#define BN_   2048
#define INDIM 1024
#define HD    256
#define OD    512
#define TN    12
#define KN    3
#define NHOPS 4
#define TP1   13

#define ER    8              // expert/gemm row tile
#define CR    16             // comb row tile

// async global -> LDS, 16B per lane (LDS dest linear in tid)
__device__ __forceinline__ void gll16(const float* g, float* l) {
  __builtin_amdgcn_global_load_lds(
      (const __attribute__((address_space(1))) void*)g,
      (__attribute__((address_space(3))) void*)l, 16, 0, 0);
}

__device__ __forceinline__ float4 ld4(const float* p) { return *(const float4*)p; }

__device__ __forceinline__ void fma4(float4& c, float a, const float4 b) {
  c.x = fmaf(a, b.x, c.x); c.y = fmaf(a, b.y, c.y);
  c.z = fmaf(a, b.z, c.z); c.w = fmaf(a, b.w, c.w);
}
__device__ __forceinline__ void add4(float4& c, const float4 b) {
  c.x += b.x; c.y += b.y; c.z += b.z; c.w += b.w;
}

// barrier-free K loop, 2-group-deep W prefetch (8 dwordx4 in flight).
// acc[NR] += A[NR rows x k-slice] @ W[k-slice x 4 cols]; nk4 even, >= 4.
template<int NR>
__device__ __forceinline__ void kloop2(float4* acc, const float* SA, int astr,
                                       const float* w0, int ws, int nk4, int ks0) {
  const float* wp = w0;
  float4 a0 = ld4(wp),          a1 = ld4(wp + ws),
         a2 = ld4(wp + 2 * ws), a3 = ld4(wp + 3 * ws);
  float4 b0 = ld4(wp + 4 * ws), b1 = ld4(wp + 5 * ws),
         b2 = ld4(wp + 6 * ws), b3 = ld4(wp + 7 * ws);
#pragma unroll 1
  for (int k4 = 0; k4 < nk4 - 2; k4 += 2) {
    float4 c0 = ld4(wp + 8 * ws),  c1 = ld4(wp + 9 * ws),
           c2 = ld4(wp + 10 * ws), c3 = ld4(wp + 11 * ws);
    const int kk = ks0 + k4 * 4;
#pragma unroll
    for (int r = 0; r < NR; ++r) {
      float4 av = *(const float4*)(SA + r * astr + kk);
      fma4(acc[r], av.x, a0); fma4(acc[r], av.y, a1);
      fma4(acc[r], av.z, a2); fma4(acc[r], av.w, a3);
    }
    float4 d0 = ld4(wp + 12 * ws), d1 = ld4(wp + 13 * ws),
           d2 = ld4(wp + 14 * ws), d3 = ld4(wp + 15 * ws);
#pragma unroll
    for (int r = 0; r < NR; ++r) {
      float4 av = *(const float4*)(SA + r * astr + kk + 4);
      fma4(acc[r], av.x, b0); fma4(acc[r], av.y, b1);
      fma4(acc[r], av.z, b2); fma4(acc[r], av.w, b3);
    }
    a0 = c0; a1 = c1; a2 = c2; a3 = c3;
    b0 = d0; b1 = d1; b2 = d2; b3 = d3;
    wp += 8 * ws;
  }
  const int kk = ks0 + (nk4 - 2) * 4;
#pragma unroll
  for (int r = 0; r < NR; ++r) {
    float4 av = *(const float4*)(SA + r * astr + kk);
    fma4(acc[r], av.x, a0); fma4(acc[r], av.y, a1);
    fma4(acc[r], av.z, a2); fma4(acc[r], av.w, a3);
  }
#pragma unroll
  for (int r = 0; r < NR; ++r) {
    float4 av = *(const float4*)(SA + r * astr + kk + 4);
    fma4(acc[r], av.x, b0); fma4(acc[r], av.y, b1);
    fma4(acc[r], av.z, b2); fma4(acc[r], av.w, b3);
  }
}

// deterministic 4-wave reduction, fixed association (0+1)+(2+3); wave 0 ends with sum
template<int NR>
__device__ __forceinline__ void reduce4(float4* acc, float4 (*pbA)[64],
                                        float4 (*pbB)[64], int w, int tx) {
  __syncthreads();
  if (w == 1) {
#pragma unroll
    for (int r = 0; r < NR; ++r) pbA[r][tx] = acc[r];
  } else if (w == 3) {
#pragma unroll
    for (int r = 0; r < NR; ++r) pbB[r][tx] = acc[r];
  }
  __syncthreads();
  if (w == 0) {
#pragma unroll
    for (int r = 0; r < NR; ++r) add4(acc[r], pbA[r][tx]);
  } else if (w == 2) {
#pragma unroll
    for (int r = 0; r < NR; ++r) add4(acc[r], pbB[r][tx]);
  }
  __syncthreads();
  if (w == 2) {
#pragma unroll
    for (int r = 0; r < NR; ++r) pbA[r][tx] = acc[r];
  }
  __syncthreads();
  if (w == 0) {
#pragma unroll
    for (int r = 0; r < NR; ++r) add4(acc[r], pbA[r][tx]);
  }
}

// ---------------- init: zero counters + build hop-0 grouping (single block) ----------------
__global__ __launch_bounds__(1024) void k_init(const int* __restrict__ init_t,
                                               int* __restrict__ cnt,
                                               int* __restrict__ gidx) {
  const int tid = threadIdx.x;
  if (tid < NHOPS * 16) cnt[tid] = 0;
  __syncthreads();
  for (int n = tid; n < BN_; n += 1024) {
    int t = init_t[n];
    int slot = atomicAdd(&cnt[t], 1);
    gidx[t * BN_ + slot] = n;
  }
}

// ---------------- gemm_in partial: pp[kh] = x[:, kh*512:+512] @ W_in[kh*512:+512, :] ----------------
__global__ __launch_bounds__(256) void k_gemm_in(const float* __restrict__ A,
                                                 const float* __restrict__ W,
                                                 float* __restrict__ pp) {
  const int bm = blockIdx.x * ER;
  const int kh = blockIdx.y;
  __shared__ float  sA[ER][512];       // 16KB
  __shared__ float4 pbA[ER][64];       // 8KB
  __shared__ float4 pbB[ER][64];       // 8KB
  const int tid = threadIdx.x;
  const int tx = tid & 63;
  const int w = tid >> 6;

#pragma unroll
  for (int l = 0; l < 4; ++l) {
    int idx = tid + l * 256;
    int r = idx >> 7;                  // wave-uniform
    int c = (idx & 127) << 2;
    gll16(&A[(size_t)(bm + r) * INDIM + kh * 512 + c], &sA[r][c]);
  }
  __syncthreads();

  float4 acc[ER];
#pragma unroll
  for (int r = 0; r < ER; ++r) acc[r] = make_float4(0.f, 0.f, 0.f, 0.f);

  const int ks = w * 128;
  kloop2<ER>(acc, &sA[0][0], 512, W + (size_t)(kh * 512 + ks) * HD + tx * 4, HD, 32, ks);
  reduce4<ER>(acc, pbA, pbB, w, tx);

  if (w == 0) {
#pragma unroll
    for (int r = 0; r < ER; ++r)
      *(float4*)&pp[((size_t)kh * BN_ + bm + r) * HD + tx * 4] = acc[r];
  }
}

// ---------------- combine gemm_in partials + bias ----------------
__global__ __launch_bounds__(256) void k_cin(const float* __restrict__ pp,
                                             const float* __restrict__ bias,
                                             float* __restrict__ states) {
  int idx = blockIdx.x * 256 + threadIdx.x;     // float4 index
  int c = (idx & 63) << 2;
  float4 a = ld4(&pp[(size_t)idx * 4]);
  float4 b = ld4(&pp[(size_t)BN_ * HD + (size_t)idx * 4]);
  float4 bv = ld4(&bias[c]);
  float4 o = make_float4(a.x + b.x + bv.x, a.y + b.y + bv.y,
                         a.z + b.z + bv.z, a.w + b.w + bv.w);
  *(float4*)&states[(size_t)idx * 4] = o;
}

// ---------------- gemm_out: out = states @ W_out + b_out ----------------
__global__ __launch_bounds__(256) void k_gemm_out(const float* __restrict__ A,
                                                  const float* __restrict__ W,
                                                  const float* __restrict__ bias,
                                                  float* __restrict__ C) {
  const int bm = blockIdx.x * ER;
  const int cb = blockIdx.y * 256;
  __shared__ float  sA[ER][HD];        // 8KB
  __shared__ float4 pbA[ER][64];
  __shared__ float4 pbB[ER][64];
  const int tid = threadIdx.x;
  const int tx = tid & 63;
  const int w = tid >> 6;

#pragma unroll
  for (int l = 0; l < 2; ++l) {
    int idx = tid + l * 256;
    int r = idx >> 6;                  // wave-uniform (w + 4l)
    int c = (idx & 63) << 2;
    gll16(&A[(size_t)(bm + r) * HD + c], &sA[r][c]);
  }
  __syncthreads();

  float4 acc[ER];
#pragma unroll
  for (int r = 0; r < ER; ++r) acc[r] = make_float4(0.f, 0.f, 0.f, 0.f);

  const int ks = w * 64;
  kloop2<ER>(acc, &sA[0][0], HD, W + (size_t)ks * OD + cb + tx * 4, OD, 16, ks);
  reduce4<ER>(acc, pbA, pbB, w, tx);

  if (w == 0) {
    float4 bv = ld4(&bias[cb + tx * 4]);
#pragma unroll
    for (int r = 0; r < ER; ++r) {
      float4 o = make_float4(acc[r].x + bv.x, acc[r].y + bv.y,
                             acc[r].z + bv.z, acc[r].w + bv.w);
      *(float4*)&C[(size_t)(bm + r) * OD + cb + tx * 4] = o;
    }
  }
}

// ---------------- fused expert: part_k[n] = wk*relu(relu(S@W1+b1)@W2+b2) ----------------
// XCD-balanced decode: 24 half-temper units (odd/even rowblocks), 3 units per XCD
// -> 1.5 tempers (2.4MB weights) per XCD L2, full worst-case row capacity.
// grid.x = 8 * 3 * 3 * 128 = 9216; 256 thr, 4 waves k-split (64 k each).
__global__ __launch_bounds__(256) void k_h1h2(
    int hop,
    const float* __restrict__ W1, const float* __restrict__ b1,
    const float* __restrict__ W2, const float* __restrict__ b2,
    const float* __restrict__ op_noise,
    const int* __restrict__ cnt, const int* __restrict__ gidx,
    const float* __restrict__ states, float* __restrict__ part) {
  const int bid = blockIdx.x;
  const int xcd = bid & 7;
  const int s   = bid >> 3;            // [0,1152)
  const int u   = xcd * 3 + (s % 3);   // unit [0,24)
  const int inner = s / 3;             // [0,384)
  const int k   = inner % 3;
  const int j   = inner / 3;           // [0,128)
  const int t   = u >> 1;
  const int h   = u & 1;
  const int rb  = j * 2 + h;           // rowblock [0,256)

  const int cntv = cnt[hop * 16 + t];
  const int r0 = rb * ER;
  if (r0 >= cntv) return;
  const int gb = (hop * TN + t) * BN_ + r0;
  const int rows = min(ER, cntv - r0);

  __shared__ float  sA[ER][HD];        // 8KB states rows
  __shared__ float  sH[ER][HD];        // 8KB h1
  __shared__ float4 pbA[ER][64];       // 8KB
  __shared__ float4 pbB[ER][64];       // 8KB  -> 32KB total
  const int tid = threadIdx.x;
  const int tx = tid & 63;
  const int w = tid >> 6;

  // gather active rows (wave-uniform r; tail rows stale -> discarded)
#pragma unroll
  for (int l = 0; l < 2; ++l) {
    int r = w + 4 * l;
    int c = tx << 2;
    if (r < rows)
      gll16(&states[(size_t)gidx[gb + r] * HD + c], &sA[r][c]);
  }
  __syncthreads();

  const float* Wa = W1 + (size_t)(t * KN + k) * HD * HD;
  const float* Wb = W2 + (size_t)(t * KN + k) * HD * HD;
  const int ks = w * 64;

  float4 acc[ER];
#pragma unroll
  for (int r = 0; r < ER; ++r) acc[r] = make_float4(0.f, 0.f, 0.f, 0.f);

  // ---- layer 1 ----
  kloop2<ER>(acc, &sA[0][0], HD, Wa + (size_t)ks * HD + tx * 4, HD, 16, ks);
  reduce4<ER>(acc, pbA, pbB, w, tx);

  if (w == 0) {
    float4 bv = ld4(&b1[(t * KN + k) * HD + tx * 4]);
#pragma unroll
    for (int r = 0; r < ER; ++r) {
      float4 hh;
      hh.x = fmaxf(acc[r].x + bv.x, 0.f);
      hh.y = fmaxf(acc[r].y + bv.y, 0.f);
      hh.z = fmaxf(acc[r].z + bv.z, 0.f);
      hh.w = fmaxf(acc[r].w + bv.w, 0.f);
      *(float4*)&sH[r][tx * 4] = hh;
    }
  }
  __syncthreads();

  // ---- layer 2 ----
#pragma unroll
  for (int r = 0; r < ER; ++r) acc[r] = make_float4(0.f, 0.f, 0.f, 0.f);
  kloop2<ER>(acc, &sH[0][0], HD, Wb + (size_t)ks * HD + tx * 4, HD, 16, ks);
  reduce4<ER>(acc, pbA, pbB, w, tx);

  if (w == 0) {
    float wkk;
    {
      const float* on = op_noise + (hop * TN + t) * KN;
      float x0 = on[0], x1 = on[1], x2 = on[2];
      float m = fmaxf(fmaxf(x0, x1), x2);
      float e0 = expf(x0 - m), e1 = expf(x1 - m), e2 = expf(x2 - m);
      float ek = (k == 0) ? e0 : (k == 1) ? e1 : e2;
      wkk = ek / (e0 + e1 + e2);
    }
    float4 bv = ld4(&b2[(t * KN + k) * HD + tx * 4]);
#pragma unroll
    for (int r = 0; r < ER; ++r) {
      if (r < rows) {
        int n = gidx[gb + r];
        float4 o;
        o.x = wkk * fmaxf(acc[r].x + bv.x, 0.f);
        o.y = wkk * fmaxf(acc[r].y + bv.y, 0.f);
        o.z = wkk * fmaxf(acc[r].z + bv.z, 0.f);
        o.w = wkk * fmaxf(acc[r].w + bv.w, 0.f);
        *(float4*)&part[((size_t)k * BN_ + n) * HD + tx * 4] = o;
      }
    }
  }
}

// ---------------- combine partials + routing + Gumbel argmax + regroup ----------------
__global__ __launch_bounds__(256) void k_comb(
    int hop,
    const float* __restrict__ Wr, const float* __restrict__ br,
    const float* __restrict__ route_u,
    int* __restrict__ cnt, int* __restrict__ gidx,
    const float* __restrict__ part,
    float* __restrict__ states) {
  const int t  = blockIdx.x % TN;
  const int rb = blockIdx.x / TN;
  const int cntv = cnt[hop * 16 + t];
  const int r0 = rb * CR;
  if (r0 >= cntv) return;
  const int gb = (hop * TN + t) * BN_ + r0;
  const int rows = min(CR, cntv - r0);

  __shared__ float sO[CR][HD + 4];
  __shared__ float sWr[HD * TP1];
  __shared__ float sL[CR][16];
  __shared__ int   sN[CR];

  const int tid = threadIdx.x;
  if (tid < CR && tid < rows) sN[tid] = gidx[gb + tid];

#pragma unroll
  for (int l = 0; l < 4; ++l) {
    int idx = tid + l * 256;
    int r = idx >> 6;
    int c = (idx & 63) << 2;
    if (r < rows) {
      int n = gidx[gb + r];
      size_t p = (size_t)n * HD + c;
      float4 a = ld4(&part[p]);
      float4 b = ld4(&part[(size_t)BN_ * HD + p]);
      float4 cc = ld4(&part[(size_t)2 * BN_ * HD + p]);
      float4 v = make_float4(a.x + b.x + cc.x, a.y + b.y + cc.y,
                             a.z + b.z + cc.z, a.w + b.w + cc.w);
      *(float4*)&sO[r][c] = v;
      *(float4*)&states[(size_t)n * HD + c] = v;
    }
  }
  for (int i = tid; i < HD * TP1; i += 256)
    sWr[i] = Wr[(size_t)t * HD * TP1 + i];
  __syncthreads();

  int r = tid >> 4, g = tid & 15;
  if (r < rows && g < TP1) {
    float a = br[t * TP1 + g];
#pragma unroll 8
    for (int f = 0; f < HD; ++f) a = fmaf(sO[r][f], sWr[f * TP1 + g], a);
    float u = route_u[((size_t)hop * BN_ + sN[r]) * TP1 + g];
    float gb_ = -logf(-logf(u + 1e-9f) + 1e-9f);
    sL[r][g] = a + gb_;
  }
  __syncthreads();

  if (tid < rows) {
    float best = sL[tid][0];
    int bj = 0;
#pragma unroll
    for (int gg = 1; gg < TP1; ++gg) {
      float v = sL[tid][gg];
      if (v > best) { best = v; bj = gg; }
    }
    // regroup into next hop (skip done rows; bj<TN => new temper = bj)
    if (hop + 1 < NHOPS && bj != TN) {
      int n = sN[tid];
      int slot = atomicAdd(&cnt[(hop + 1) * 16 + bj], 1);
      gidx[((hop + 1) * TN + bj) * BN_ + slot] = n;
    }
  }
}

// ---------------- launcher ----------------
extern "C" void kernel_launch(void* const* d_in, const int* in_sizes, int n_in,
                              void* d_out, int out_size, void* d_ws, size_t ws_size,
                              hipStream_t stream) {
  const float* x        = (const float*)d_in[0];
  const int*   init_t   = (const int*)d_in[1];
  const float* op_noise = (const float*)d_in[2];
  const float* route_u  = (const float*)d_in[3];
  const float* W_in     = (const float*)d_in[4];
  const float* b_in     = (const float*)d_in[5];
  const float* W1       = (const float*)d_in[6];
  const float* b1       = (const float*)d_in[7];
  const float* W2       = (const float*)d_in[8];
  const float* b2       = (const float*)d_in[9];
  const float* Wr       = (const float*)d_in[10];
  const float* br       = (const float*)d_in[11];
  const float* W_out    = (const float*)d_in[12];
  const float* b_out    = (const float*)d_in[13];
  float* out = (float*)d_out;

  float* states = (float*)d_ws;                       // 2MB
  float* part   = states + (size_t)BN_ * HD;          // [KN][BN_][HD] 6MB
  float* pp     = part;                               // gemm_in partials alias (4MB)
  int* cnt  = (int*)(part + (size_t)KN * BN_ * HD);   // [NHOPS][16]
  int* gidx = cnt + NHOPS * 16;                       // [NHOPS][TN][BN_]

  k_init<<<1, 1024, 0, stream>>>(init_t, cnt, gidx);

  k_gemm_in<<<dim3(BN_ / ER, 2), 256, 0, stream>>>(x, W_in, pp);
  k_cin<<<(BN_ * HD / 4) / 256, 256, 0, stream>>>(pp, b_in, states);

  for (int hop = 0; hop < NHOPS; ++hop) {
    k_h1h2<<<8 * 3 * 3 * 128, 256, 0, stream>>>(
        hop, W1, b1, W2, b2, op_noise, cnt, gidx, states, part);
    k_comb<<<TN * (BN_ / CR), 256, 0, stream>>>(
        hop, Wr, br, route_u, cnt, gidx, part, states);
  }

  k_gemm_out<<<dim3(BN_ / ER, OD / 256), 256, 0, stream>>>(states, W_out, b_out, out);
}